// Round 4
// baseline (317.712 us; speedup 1.0000x reference)
//
#include <hip/hip_runtime.h>

// ---- problem constants ----
#define Bb_ 2
#define S_ 2048
#define D_ 512
#define H_ 8
#define DH_ 64

typedef __attribute__((ext_vector_type(8))) __bf16 bf16x8;
typedef __attribute__((ext_vector_type(4))) __bf16 bf16x4;
typedef __attribute__((ext_vector_type(2))) __bf16 bf16x2;
typedef __attribute__((ext_vector_type(4))) float f32x4;
typedef __attribute__((ext_vector_type(8))) short short8;

#define SWZ(r) (((r) & 7) << 4)

// ---------------- weight transpose + bf16 convert ----------------
__global__ __launch_bounds__(256) void wtrans_kernel(const float* __restrict__ w,
                                                     __bf16* __restrict__ wt,
                                                     int K, int N) {
  int idx = blockIdx.x * 256 + threadIdx.x;
  if (idx >= K * N) return;
  int k = idx / N, n = idx - k * N;
  wt[(long)n * K + k] = (__bf16)w[idx];
}

// ---------------- layernorm (ddof=0), row length 512 ----------------
__global__ __launch_bounds__(256) void ln_kernel(const float* __restrict__ x,
                                                 const float* __restrict__ w,
                                                 const float* __restrict__ b,
                                                 __bf16* __restrict__ out) {
  long row = blockIdx.x;
  const float* xr = x + row * 512;
  int t = threadIdx.x;
  float2 v = *reinterpret_cast<const float2*>(xr + t * 2);
  float s = v.x + v.y;
  float sq = v.x * v.x + v.y * v.y;
#pragma unroll
  for (int m = 1; m < 64; m <<= 1) {
    s += __shfl_xor(s, m);
    sq += __shfl_xor(sq, m);
  }
  __shared__ float red[8];
  int wid = t >> 6;
  if ((t & 63) == 0) { red[wid] = s; red[wid + 4] = sq; }
  __syncthreads();
  s = red[0] + red[1] + red[2] + red[3];
  sq = red[4] + red[5] + red[6] + red[7];
  float mu = s * (1.f / 512.f);
  float var = sq * (1.f / 512.f) - mu * mu;
  float rs = rsqrtf(var + 1e-5f);
  int c = t * 2;
  float o0 = (v.x - mu) * rs * w[c] + b[c];
  float o1 = (v.y - mu) * rs * w[c + 1] + b[c + 1];
  __bf16* op = out + row * 512 + c;
  op[0] = (__bf16)o0;
  op[1] = (__bf16)o1;
}

// ---------------- generic bf16 MFMA GEMM ----------------
// OUTMODE: 0 = fp32 out, 1 = bf16 out,
//          2 = qkv scatter: col<512 -> Qn, 512..1023 -> Kn, >=1024 -> Vt(B,H,64,S)
template <int ACT, int OUTMODE, bool HASRES>
__global__ __launch_bounds__(256) void gemm_kernel(
    const __bf16* __restrict__ A, const __bf16* __restrict__ Bt,
    const float* __restrict__ bias, const float* __restrict__ res,
    float* __restrict__ outF, __bf16* __restrict__ outB,
    __bf16* __restrict__ outK, __bf16* __restrict__ outVt,
    int lda, int ldb, int ldc, int K) {
  __shared__ __align__(16) __bf16 As[128 * 64];
  __shared__ __align__(16) __bf16 Bs[128 * 64];
  int t = threadIdx.x, lane = t & 63, wid = t >> 6;
  const __bf16* Ab = A + (long)blockIdx.y * 128 * lda;
  const __bf16* Bb = Bt + (long)blockIdx.x * 128 * ldb;

  f32x4 acc[4][4];
#pragma unroll
  for (int i = 0; i < 4; i++)
#pragma unroll
    for (int j = 0; j < 4; j++) acc[i][j] = (f32x4){0.f, 0.f, 0.f, 0.f};

  int wr = wid >> 1, wc = wid & 1;
  int kq = lane >> 4;

  for (int k0 = 0; k0 < K; k0 += 64) {
    __syncthreads();
#pragma unroll
    for (int i = 0; i < 4; i++) {
      int ci = i * 256 + t;
      int row = ci >> 3;
      int c = ci & 7;
      int sc = c ^ (row & 7);
      short8 va = *reinterpret_cast<const short8*>(Ab + (long)row * lda + k0 + sc * 8);
      *reinterpret_cast<short8*>(&As[row * 64 + c * 8]) = va;
      short8 vb = *reinterpret_cast<const short8*>(Bb + (long)row * ldb + k0 + sc * 8);
      *reinterpret_cast<short8*>(&Bs[row * 64 + c * 8]) = vb;
    }
    __syncthreads();
#pragma unroll
    for (int ks = 0; ks < 2; ks++) {
      bf16x8 af[4], bfr[4];
#pragma unroll
      for (int fm = 0; fm < 4; fm++) {
        int r = wr * 64 + fm * 16 + (lane & 15);
        int c = (ks * 4 + kq) ^ (r & 7);
        af[fm] = *reinterpret_cast<const bf16x8*>(&As[r * 64 + c * 8]);
      }
#pragma unroll
      for (int fn = 0; fn < 4; fn++) {
        int r = wc * 64 + fn * 16 + (lane & 15);
        int c = (ks * 4 + kq) ^ (r & 7);
        bfr[fn] = *reinterpret_cast<const bf16x8*>(&Bs[r * 64 + c * 8]);
      }
#pragma unroll
      for (int fm = 0; fm < 4; fm++)
#pragma unroll
        for (int fn = 0; fn < 4; fn++)
          acc[fm][fn] = __builtin_amdgcn_mfma_f32_16x16x32_bf16(af[fm], bfr[fn],
                                                                acc[fm][fn], 0, 0, 0);
    }
  }

  long gr0 = (long)blockIdx.y * 128 + wr * 64;
  long gc0 = (long)blockIdx.x * 128 + wc * 64;
#pragma unroll
  for (int fm = 0; fm < 4; fm++)
#pragma unroll
    for (int fn = 0; fn < 4; fn++) {
      int col = (int)gc0 + fn * 16 + (lane & 15);
      long rbase = gr0 + fm * 16 + kq * 4;
      float bv = bias ? bias[col] : 0.f;
#pragma unroll
      for (int r4 = 0; r4 < 4; r4++) {
        long grow = rbase + r4;
        float v = acc[fm][fn][r4] + bv;
        if (HASRES) v += res[grow * ldc + col];
        if (ACT == 1) v = fmaxf(v, 0.f);
        if (ACT == 2) v = 0.5f * v * (1.f + erff(v * 0.70710678118f));
        if (OUTMODE == 0) {
          outF[grow * ldc + col] = v;
        } else if (OUTMODE == 1) {
          outB[grow * ldc + col] = (__bf16)v;
        } else {
          if (col < 512) {
            outB[grow * 512 + col] = (__bf16)v;            // Q natural
          } else if (col < 1024) {
            outK[grow * 512 + (col - 512)] = (__bf16)v;    // K natural
          } else {
            int dh = col - 1024;
            int h = dh >> 6, d = dh & 63;
            long bb = grow >> 11;
            long srow = grow & 2047;
            outVt[(((bb * 8 + h) * 64 + d) << 11) + srow] = (__bf16)v;  // V^T
          }
        }
      }
    }
}

// ---------------- fused attention: QK^T + map_norm + sinmax + scores + PV ----
// Block = 16 q-rows of one (b,h), 512 threads = 8 waves; wave wv owns k-cols
// [wv*256, wv*256+256). Swapped MFMA: D[row=k,col=q] so lane ln owns q-row ln.
// Pass 0: stats (in-lane). Pass 1: recompute + sin -> bf16 stash (swizzled) + Z.
// Then: normalized fp32 scores write; swapped PV from stash; cross-wave reduce.
__global__ __launch_bounds__(512, 4) void fused_attn_kernel(
    const __bf16* __restrict__ Qn, const __bf16* __restrict__ Kn,
    const __bf16* __restrict__ vt, float* __restrict__ sco,
    __bf16* __restrict__ hv) {
  __shared__ __align__(16) __bf16 stash[16 * 2048];       // 64 KB
  __shared__ float red_s[8][16], red_q[8][16], red2[8][16];

  // XCD-aware swizzle: 2048 blocks % 8 == 0 -> bijective; head's K/V stay in L2
  int bid = blockIdx.x;
  int xcd = bid & 7, jj = bid >> 3;
  int head = xcd * 2 + (jj >> 7);     // 0..15 = bb*8+hh
  int sub = jj & 127;
  int bb = head >> 3, hh = head & 7;
  int q0 = sub << 4;

  int t = threadIdx.x;
  int lane = t & 63, wv = t >> 6;
  int cg = lane >> 4, ln = lane & 15;
  int swzl = SWZ(ln);

  // Q B-frags (held all passes): lane ln -> Q row q0+ln
  const __bf16* Qrow = Qn + (long)(bb * 2048 + q0 + ln) * 512 + hh * 64;
  bf16x8 qf0 = *reinterpret_cast<const bf16x8*>(Qrow + cg * 8);
  bf16x8 qf1 = *reinterpret_cast<const bf16x8*>(Qrow + 32 + cg * 8);

  const __bf16* Kb = Kn + (long)bb * 2048 * 512 + hh * 64;
  int k_base = wv * 256;

  // ---- pass 0: row stats (in-lane; lane owns q-row ln) ----
  float ss = 0.f, qq = 0.f;
#pragma unroll
  for (int tl = 0; tl < 16; tl++) {
    const __bf16* Kr = Kb + (long)(k_base + tl * 16 + ln) * 512;
    bf16x8 kf0 = *reinterpret_cast<const bf16x8*>(Kr + cg * 8);
    bf16x8 kf1 = *reinterpret_cast<const bf16x8*>(Kr + 32 + cg * 8);
    f32x4 d = (f32x4){0.f, 0.f, 0.f, 0.f};
    d = __builtin_amdgcn_mfma_f32_16x16x32_bf16(kf0, qf0, d, 0, 0, 0);
    d = __builtin_amdgcn_mfma_f32_16x16x32_bf16(kf1, qf1, d, 0, 0, 0);
    ss += d[0] + d[1] + d[2] + d[3];
    qq += d[0] * d[0] + d[1] * d[1] + d[2] * d[2] + d[3] * d[3];
  }
  ss += __shfl_xor(ss, 16); ss += __shfl_xor(ss, 32);
  qq += __shfl_xor(qq, 16); qq += __shfl_xor(qq, 32);
  if (lane < 16) { red_s[wv][ln] = ss; red_q[wv][ln] = qq; }
  __syncthreads();
  float s8 = 0.f, q8 = 0.f;
#pragma unroll
  for (int w = 0; w < 8; w++) { s8 += red_s[w][ln]; q8 += red_q[w][ln]; }
  float mu = s8 * (1.f / 2048.f);
  float var = (q8 - 2048.f * mu * mu) * (1.f / 2047.f);
  float rs = rsqrtf(var + 1e-5f);

  // ---- pass 1: recompute QK, sin, stash bf16 (swizzled), Z in-lane ----
  float Z = 0.f;
  char* myrow = reinterpret_cast<char*>(stash) + ln * 4096;
  int kb2 = k_base * 2;
#pragma unroll
  for (int w = 0; w < 8; w++) {
    int kb = k_base + w * 32;
    const __bf16* Kr0 = Kb + (long)(kb + ln) * 512;
    const __bf16* Kr1 = Kb + (long)(kb + 16 + ln) * 512;
    f32x4 d0 = (f32x4){0.f, 0.f, 0.f, 0.f}, d1 = (f32x4){0.f, 0.f, 0.f, 0.f};
    d0 = __builtin_amdgcn_mfma_f32_16x16x32_bf16(
        *reinterpret_cast<const bf16x8*>(Kr0 + cg * 8), qf0, d0, 0, 0, 0);
    d0 = __builtin_amdgcn_mfma_f32_16x16x32_bf16(
        *reinterpret_cast<const bf16x8*>(Kr0 + 32 + cg * 8), qf1, d0, 0, 0, 0);
    d1 = __builtin_amdgcn_mfma_f32_16x16x32_bf16(
        *reinterpret_cast<const bf16x8*>(Kr1 + cg * 8), qf0, d1, 0, 0, 0);
    d1 = __builtin_amdgcn_mfma_f32_16x16x32_bf16(
        *reinterpret_cast<const bf16x8*>(Kr1 + 32 + cg * 8), qf1, d1, 0, 0, 0);
    bf16x4 w0, w1;
#pragma unroll
    for (int r4 = 0; r4 < 4; r4++) {
      float p0 = 1.f + __sinf(1.25f * (d0[r4] - mu) * rs);
      float p1 = 1.f + __sinf(1.25f * (d1[r4] - mu) * rs);
      Z += p0 + p1;
      w0[r4] = (__bf16)p0;
      w1[r4] = (__bf16)p1;
    }
    int boff = kb2 + w * 64 + cg * 8;
    *reinterpret_cast<bf16x4*>(myrow + (boff ^ swzl)) = w0;
    *reinterpret_cast<bf16x4*>(myrow + ((boff + 32) ^ swzl)) = w1;
  }
  Z += __shfl_xor(Z, 16); Z += __shfl_xor(Z, 32);
  if (lane < 16) red2[wv][ln] = Z;
  __syncthreads();  // barrier A: stash + red2 ready

  // ---- scores write: normalized fp32, coalesced ----
  {
    int r = t >> 5, c0 = t & 31;
    float z8 = 0.f;
#pragma unroll
    for (int w = 0; w < 8; w++) z8 += red2[w][r];
    float invZ = 1.f / z8;
    const char* rrow = reinterpret_cast<const char*>(stash) + r * 4096;
    int swzr = SWZ(r);
    float* srow = sco + ((long)head * 2048 + q0 + r) * 2048;
#pragma unroll
    for (int j = 0; j < 8; j++) {
      int chunk = c0 + j * 32;
      bf16x8 v = *reinterpret_cast<const bf16x8*>(rrow + ((chunk * 16) ^ swzr));
      float4 o0, o1;
      o0.x = (float)v[0] * invZ; o0.y = (float)v[1] * invZ;
      o0.z = (float)v[2] * invZ; o0.w = (float)v[3] * invZ;
      o1.x = (float)v[4] * invZ; o1.y = (float)v[5] * invZ;
      o1.z = (float)v[6] * invZ; o1.w = (float)v[7] * invZ;
      *reinterpret_cast<float4*>(srow + chunk * 8) = o0;
      *reinterpret_cast<float4*>(srow + chunk * 8 + 4) = o1;
    }
  }

  // ---- PV (swapped): hvT[d][q] += V^T-frag x P-frag, from stash ----
  f32x4 hacc[4];
#pragma unroll
  for (int dt = 0; dt < 4; dt++) hacc[dt] = (f32x4){0.f, 0.f, 0.f, 0.f};
  {
    float z8 = 0.f;
#pragma unroll
    for (int w = 0; w < 8; w++) z8 += red2[w][ln];
    float invZ = 1.f / z8;
    const __bf16* vhead = vt + (long)head * 64 * 2048;
    const char* prow = reinterpret_cast<const char*>(stash) + ln * 4096;
#pragma unroll
    for (int w = 0; w < 8; w++) {
      int kb = k_base + w * 32;
      bf16x8 pfrag = *reinterpret_cast<const bf16x8*>(
          prow + ((kb2 + w * 64 + cg * 16) ^ swzl));
#pragma unroll
      for (int dt = 0; dt < 4; dt++) {
        bf16x8 vf = *reinterpret_cast<const bf16x8*>(
            vhead + (long)(dt * 16 + ln) * 2048 + kb + cg * 8);
        hacc[dt] = __builtin_amdgcn_mfma_f32_16x16x32_bf16(vf, pfrag, hacc[dt], 0, 0, 0);
      }
    }
#pragma unroll
    for (int dt = 0; dt < 4; dt++)
#pragma unroll
      for (int r4 = 0; r4 < 4; r4++) hacc[dt][r4] *= invZ;
  }
  __syncthreads();  // barrier B: all stash reads done

  // write hvT partials into stash region (fp32, [wv][q=ln][d] swizzled 16B)
  {
    char* hbase = reinterpret_cast<char*>(stash) + wv * 4096 + ln * 256;
#pragma unroll
    for (int dt = 0; dt < 4; dt++) {
      int doff = (dt * 16 + cg * 4) * 4;
      *reinterpret_cast<f32x4*>(hbase + (doff ^ swzl)) = hacc[dt];
    }
  }
  __syncthreads();  // barrier C

  // reduce 8 partials, write hv bf16: thread t -> (q = t>>5, d0 = (t&31)*2)
  {
    int q = t >> 5, d0 = (t & 31) * 2;
    int swzq = SWZ(q);
    int slot = ((d0 & ~3) * 4) ^ swzq;
    int rem = (d0 & 3) * 4;
    float a0 = 0.f, a1 = 0.f;
#pragma unroll
    for (int w = 0; w < 8; w++) {
      const char* p = reinterpret_cast<const char*>(stash) + w * 4096 + q * 256 + slot + rem;
      float2 vv = *reinterpret_cast<const float2*>(p);
      a0 += vv.x; a1 += vv.y;
    }
    bf16x2 hw;
    hw[0] = (__bf16)a0; hw[1] = (__bf16)a1;
    *reinterpret_cast<bf16x2*>(hv + (long)(bb * 2048 + q0 + q) * 512 + hh * 64 + d0) = hw;
  }
}

// ---------------- launch ----------------
extern "C" void kernel_launch(void* const* d_in, const int* in_sizes, int n_in,
                              void* d_out, int out_size, void* d_ws, size_t ws_size,
                              hipStream_t stream) {
  const float* x = (const float*)d_in[0];
  const float* norm_w = (const float*)d_in[1];
  const float* norm_b = (const float*)d_in[2];
  const float* qvk_w = (const float*)d_in[3];
  const float* qvk_b = (const float*)d_in[4];
  const float* concat_w = (const float*)d_in[5];
  const float* concat_b = (const float*)d_in[6];
  const float* mlp_norm_w = (const float*)d_in[7];
  const float* mlp_norm_b = (const float*)d_in[8];
  const float* mlp1_w = (const float*)d_in[9];
  const float* mlp1_b = (const float*)d_in[10];
  const float* mlp2_w = (const float*)d_in[11];
  const float* mlp2_b = (const float*)d_in[12];

  char* ws = (char*)d_ws;
  __bf16* qvk_wT = (__bf16*)(ws + 0);          // 1536x512
  __bf16* concat_wT = (__bf16*)(ws + 1572864); // 512x512
  __bf16* mlp1_wT = (__bf16*)(ws + 2097152);   // 1024x512
  __bf16* mlp2_wT = (__bf16*)(ws + 3145728);   // 512x1024
  __bf16* xn = (__bf16*)(ws + 4194304);        // 4096x512
  __bf16* Qn = (__bf16*)(ws + 8388608);        // 4096x512
  __bf16* Kn = (__bf16*)(ws + 12582912);       // 4096x512
  __bf16* vt = (__bf16*)(ws + 16777216);       // (B,H,64,2048)
  __bf16* hv = (__bf16*)(ws + 20971520);       // 4096x512
  float* attout = (float*)(ws + 25165824);     // 4096x512 fp32
  __bf16* a_b = (__bf16*)(ws + 33554432);      // 4096x512
  __bf16* h_b = (__bf16*)(ws + 37748736);      // 4096x1024

  float* out0 = (float*)d_out;
  float* sco = out0 + 2097152;  // scores (B,H,S,S) fp32

  wtrans_kernel<<<3072, 256, 0, stream>>>(qvk_w, qvk_wT, 512, 1536);
  wtrans_kernel<<<1024, 256, 0, stream>>>(concat_w, concat_wT, 512, 512);
  wtrans_kernel<<<2048, 256, 0, stream>>>(mlp1_w, mlp1_wT, 512, 1024);
  wtrans_kernel<<<2048, 256, 0, stream>>>(mlp2_w, mlp2_wT, 1024, 512);

  ln_kernel<<<4096, 256, 0, stream>>>(x, norm_w, norm_b, xn);

  // qkv = relu(xn @ qvk_w + b); Q,K natural; V transposed
  gemm_kernel<1, 2, false><<<dim3(12, 32), 256, 0, stream>>>(
      xn, qvk_wT, qvk_b, nullptr, nullptr, Qn, Kn, vt, 512, 512, 1536, 512);

  // fused attention (scores -> out1, hv bf16)
  fused_attn_kernel<<<2048, 512, 0, stream>>>(Qn, Kn, vt, sco, hv);

  // attout = hv @ concat_w + b + x (fp32)
  gemm_kernel<0, 0, true><<<dim3(4, 32), 256, 0, stream>>>(
      hv, concat_wT, concat_b, x, attout, nullptr, nullptr, nullptr, 512, 512, 512, 512);

  ln_kernel<<<4096, 256, 0, stream>>>(attout, mlp_norm_w, mlp_norm_b, a_b);

  // h = gelu(a @ mlp1_w + b)
  gemm_kernel<2, 1, false><<<dim3(8, 32), 256, 0, stream>>>(
      a_b, mlp1_wT, mlp1_b, nullptr, nullptr, h_b, nullptr, nullptr, 512, 512, 1024, 512);

  // out0 = h @ mlp2_w + b + attout
  gemm_kernel<0, 0, true><<<dim3(4, 32), 256, 0, stream>>>(
      h_b, mlp2_wT, mlp2_b, attout, out0, nullptr, nullptr, nullptr, 1024, 1024, 512, 1024);
}

// Round 5
// 266.691 us; speedup vs baseline: 1.1913x; 1.1913x over previous
//
#include <hip/hip_runtime.h>

// ---- problem constants ----
#define Bb_ 2
#define S_ 2048
#define D_ 512
#define H_ 8
#define DH_ 64

typedef __attribute__((ext_vector_type(8))) __bf16 bf16x8;
typedef __attribute__((ext_vector_type(4))) __bf16 bf16x4;
typedef __attribute__((ext_vector_type(2))) __bf16 bf16x2;
typedef __attribute__((ext_vector_type(4))) float f32x4;
typedef __attribute__((ext_vector_type(8))) short short8;

#define SWZ(r) (((r) & 7) << 4)

// ---------------- weight transpose + bf16 convert ----------------
__global__ __launch_bounds__(256) void wtrans_kernel(const float* __restrict__ w,
                                                     __bf16* __restrict__ wt,
                                                     int K, int N) {
  int idx = blockIdx.x * 256 + threadIdx.x;
  if (idx >= K * N) return;
  int k = idx / N, n = idx - k * N;
  wt[(long)n * K + k] = (__bf16)w[idx];
}

// ---------------- layernorm (ddof=0), row length 512 ----------------
__global__ __launch_bounds__(256) void ln_kernel(const float* __restrict__ x,
                                                 const float* __restrict__ w,
                                                 const float* __restrict__ b,
                                                 __bf16* __restrict__ out) {
  long row = blockIdx.x;
  const float* xr = x + row * 512;
  int t = threadIdx.x;
  float2 v = *reinterpret_cast<const float2*>(xr + t * 2);
  float s = v.x + v.y;
  float sq = v.x * v.x + v.y * v.y;
#pragma unroll
  for (int m = 1; m < 64; m <<= 1) {
    s += __shfl_xor(s, m);
    sq += __shfl_xor(sq, m);
  }
  __shared__ float red[8];
  int wid = t >> 6;
  if ((t & 63) == 0) { red[wid] = s; red[wid + 4] = sq; }
  __syncthreads();
  s = red[0] + red[1] + red[2] + red[3];
  sq = red[4] + red[5] + red[6] + red[7];
  float mu = s * (1.f / 512.f);
  float var = sq * (1.f / 512.f) - mu * mu;
  float rs = rsqrtf(var + 1e-5f);
  int c = t * 2;
  float o0 = (v.x - mu) * rs * w[c] + b[c];
  float o1 = (v.y - mu) * rs * w[c + 1] + b[c + 1];
  __bf16* op = out + row * 512 + c;
  op[0] = (__bf16)o0;
  op[1] = (__bf16)o1;
}

// ---------------- generic bf16 MFMA GEMM ----------------
// OUTMODE: 0 = fp32 out, 1 = bf16 out,
//          2 = qkv scatter: col<512 -> Qh (B,H,S,64); 512..1023 -> Kh (B,H,S,64);
//              >=1024 -> Vp panels: head*131072 + (k>>5)*2048 + d*32 + (k&31)
template <int ACT, int OUTMODE, bool HASRES>
__global__ __launch_bounds__(256) void gemm_kernel(
    const __bf16* __restrict__ A, const __bf16* __restrict__ Bt,
    const float* __restrict__ bias, const float* __restrict__ res,
    float* __restrict__ outF, __bf16* __restrict__ outB,
    __bf16* __restrict__ outK, __bf16* __restrict__ outVt,
    int lda, int ldb, int ldc, int K) {
  __shared__ __align__(16) __bf16 As[128 * 64];
  __shared__ __align__(16) __bf16 Bs[128 * 64];
  int t = threadIdx.x, lane = t & 63, wid = t >> 6;
  const __bf16* Ab = A + (long)blockIdx.y * 128 * lda;
  const __bf16* Bb = Bt + (long)blockIdx.x * 128 * ldb;

  f32x4 acc[4][4];
#pragma unroll
  for (int i = 0; i < 4; i++)
#pragma unroll
    for (int j = 0; j < 4; j++) acc[i][j] = (f32x4){0.f, 0.f, 0.f, 0.f};

  int wr = wid >> 1, wc = wid & 1;
  int kq = lane >> 4;

  for (int k0 = 0; k0 < K; k0 += 64) {
    __syncthreads();
#pragma unroll
    for (int i = 0; i < 4; i++) {
      int ci = i * 256 + t;
      int row = ci >> 3;
      int c = ci & 7;
      int sc = c ^ (row & 7);
      short8 va = *reinterpret_cast<const short8*>(Ab + (long)row * lda + k0 + sc * 8);
      *reinterpret_cast<short8*>(&As[row * 64 + c * 8]) = va;
      short8 vb = *reinterpret_cast<const short8*>(Bb + (long)row * ldb + k0 + sc * 8);
      *reinterpret_cast<short8*>(&Bs[row * 64 + c * 8]) = vb;
    }
    __syncthreads();
#pragma unroll
    for (int ks = 0; ks < 2; ks++) {
      bf16x8 af[4], bfr[4];
#pragma unroll
      for (int fm = 0; fm < 4; fm++) {
        int r = wr * 64 + fm * 16 + (lane & 15);
        int c = (ks * 4 + kq) ^ (r & 7);
        af[fm] = *reinterpret_cast<const bf16x8*>(&As[r * 64 + c * 8]);
      }
#pragma unroll
      for (int fn = 0; fn < 4; fn++) {
        int r = wc * 64 + fn * 16 + (lane & 15);
        int c = (ks * 4 + kq) ^ (r & 7);
        bfr[fn] = *reinterpret_cast<const bf16x8*>(&Bs[r * 64 + c * 8]);
      }
#pragma unroll
      for (int fm = 0; fm < 4; fm++)
#pragma unroll
        for (int fn = 0; fn < 4; fn++)
          acc[fm][fn] = __builtin_amdgcn_mfma_f32_16x16x32_bf16(af[fm], bfr[fn],
                                                                acc[fm][fn], 0, 0, 0);
    }
  }

  long gr0 = (long)blockIdx.y * 128 + wr * 64;
  long gc0 = (long)blockIdx.x * 128 + wc * 64;
#pragma unroll
  for (int fm = 0; fm < 4; fm++)
#pragma unroll
    for (int fn = 0; fn < 4; fn++) {
      int col = (int)gc0 + fn * 16 + (lane & 15);
      long rbase = gr0 + fm * 16 + kq * 4;
      float bv = bias ? bias[col] : 0.f;
#pragma unroll
      for (int r4 = 0; r4 < 4; r4++) {
        long grow = rbase + r4;
        float v = acc[fm][fn][r4] + bv;
        if (HASRES) v += res[grow * ldc + col];
        if (ACT == 1) v = fmaxf(v, 0.f);
        if (ACT == 2) v = 0.5f * v * (1.f + erff(v * 0.70710678118f));
        if (OUTMODE == 0) {
          outF[grow * ldc + col] = v;
        } else if (OUTMODE == 1) {
          outB[grow * ldc + col] = (__bf16)v;
        } else {
          long bbq = grow >> 11, srow = grow & 2047;
          if (col < 512) {
            int h = col >> 6, d = col & 63;
            outB[((bbq * 8 + h) * 2048 + srow) * 64 + d] = (__bf16)v;   // Qh
          } else if (col < 1024) {
            int dh = col - 512;
            int h = dh >> 6, d = dh & 63;
            outK[((bbq * 8 + h) * 2048 + srow) * 64 + d] = (__bf16)v;   // Kh
          } else {
            int dh = col - 1024;
            int h = dh >> 6, d = dh & 63;
            outVt[(bbq * 8 + h) * 131072 + (srow >> 5) * 2048 + d * 32 + (srow & 31)] = (__bf16)v;  // Vp
          }
        }
      }
    }
}

// ---------------- Gram partials: per (head, 64-k chunk) G-part + kbar-part ----
__global__ __launch_bounds__(256) void gram_kernel(const __bf16* __restrict__ Kh,
                                                   float* __restrict__ gpart,
                                                   float* __restrict__ kpart) {
  int head = blockIdx.x >> 5, chunk = blockIdx.x & 31;
  __shared__ __align__(16) __bf16 kl[64 * 64];
  int t = threadIdx.x;
  const __bf16* src = Kh + ((long)head * 2048 + chunk * 64) * 64;
#pragma unroll
  for (int i = 0; i < 2; i++) {
    int e = (i * 256 + t) * 8;
    *reinterpret_cast<short8*>(&kl[e]) = *reinterpret_cast<const short8*>(&src[e]);
  }
  __syncthreads();
  int d1 = t & 63, g = t >> 6;
  float acc[16];
#pragma unroll
  for (int i = 0; i < 16; i++) acc[i] = 0.f;
  float kb = 0.f;
  for (int r = 0; r < 64; r++) {
    float k1 = (float)kl[r * 64 + d1];
    kb += k1;
    bf16x8 a = *reinterpret_cast<const bf16x8*>(&kl[r * 64 + g * 16]);
    bf16x8 b = *reinterpret_cast<const bf16x8*>(&kl[r * 64 + g * 16 + 8]);
#pragma unroll
    for (int i = 0; i < 8; i++) acc[i] += k1 * (float)a[i];
#pragma unroll
    for (int i = 0; i < 8; i++) acc[8 + i] += k1 * (float)b[i];
  }
  float* gp = gpart + ((long)chunk * 16 + head) * 4096 + d1 * 64 + g * 16;
#pragma unroll
  for (int i = 0; i < 16; i++) gp[i] = acc[i];
  if (g == 0) kpart[(chunk * 16 + head) * 64 + d1] = kb;
}

// ---------------- reduce Gram partials -> G (fp32), kbar ----------------
__global__ __launch_bounds__(256) void greduce_kernel(const float* __restrict__ gpart,
                                                      const float* __restrict__ kpart,
                                                      float* __restrict__ G,
                                                      float* __restrict__ kbar) {
  int idx = blockIdx.x * 256 + threadIdx.x;
  if (idx < 65536) {
    int head = idx >> 12, e = idx & 4095;
    float s = 0.f;
#pragma unroll 4
    for (int c = 0; c < 32; c++) s += gpart[((long)c * 16 + head) * 4096 + e];
    G[idx] = s;
  } else if (idx < 66560) {
    int k = idx - 65536;
    int head = k >> 6, d = k & 63;
    float s = 0.f;
#pragma unroll 4
    for (int c = 0; c < 32; c++) s += kpart[(c * 16 + head) * 64 + d];
    kbar[k] = s * (1.f / 2048.f);
  }
}

// ---------------- per-row stats: mu = q.kbar ; s2 = q^T G q -> (mu, rsqrt) ----
__global__ __launch_bounds__(256, 4) void stats_kernel(const __bf16* __restrict__ Qh,
                                                       const float* __restrict__ G,
                                                       const float* __restrict__ kbar,
                                                       float2* __restrict__ stats) {
  int head = blockIdx.x >> 5, sub = blockIdx.x & 31;
  __shared__ float Gl[4096];
  __shared__ float kbl[64];
  __shared__ __align__(16) float qlf[64 * 68];
  int t = threadIdx.x;
  const float* Gsrc = G + head * 4096;
#pragma unroll
  for (int i = 0; i < 4; i++) {
    int e = (i * 256 + t) * 4;
    *reinterpret_cast<float4*>(&Gl[e]) = *reinterpret_cast<const float4*>(&Gsrc[e]);
  }
  if (t < 16)
    *reinterpret_cast<float4*>(&kbl[t * 4]) =
        *reinterpret_cast<const float4*>(&kbar[head * 64 + t * 4]);
  const __bf16* qsrc = Qh + ((long)head * 2048 + sub * 64) * 64;
#pragma unroll
  for (int i = 0; i < 2; i++) {
    int e = (i * 256 + t) * 8;
    bf16x8 v = *reinterpret_cast<const bf16x8*>(&qsrc[e]);
    int row = e >> 6, col = e & 63;
    float* dst = &qlf[row * 68 + col];
#pragma unroll
    for (int j = 0; j < 8; j++) dst[j] = (float)v[j];
  }
  __syncthreads();
  int qrow = t >> 2, qt = t & 3;
  const float* qr = &qlf[qrow * 68];
  float mup = 0.f, s2p = 0.f;
#pragma unroll
  for (int i = 0; i < 16; i++) {
    int d1 = qt * 16 + i;
    const float* Gr = &Gl[d1 * 64];
    float acc = 0.f;
#pragma unroll
    for (int j = 0; j < 64; j++) acc += Gr[j] * qr[j];
    float q1 = qr[d1];
    s2p += q1 * acc;
    mup += q1 * kbl[d1];
  }
  mup += __shfl_xor(mup, 1); mup += __shfl_xor(mup, 2);
  s2p += __shfl_xor(s2p, 1); s2p += __shfl_xor(s2p, 2);
  if (qt == 0) {
    float mu = mup;
    float var = (s2p - 2048.f * mu * mu) * (1.f / 2047.f);
    stats[(head << 11) + sub * 64 + qrow] = make_float2(mu, rsqrtf(var + 1e-5f));
  }
}

// ---------------- fused attention (single pass): QK + sinmax + scores + PV ----
// Block = 16 q-rows of one head, 512 threads = 8 waves; wave wv owns k-slice
// [wv*256, wv*256+256). Swapped MFMA D[row=k,col=q]; lane ln owns q-row ln.
// Stats precomputed. K head-contig (dense 2KB frag windows); V in 32-k panels.
__global__ __launch_bounds__(512, 4) void attn2_kernel(
    const __bf16* __restrict__ Qh, const __bf16* __restrict__ Kh,
    const __bf16* __restrict__ Vp, const float2* __restrict__ stats,
    float* __restrict__ sco, __bf16* __restrict__ hv) {
  __shared__ __align__(16) __bf16 stash[16 * 2048];   // 64 KB
  __shared__ float red2[8][16];

  int bid = blockIdx.x;
  int xcd = bid & 7, jj = bid >> 3;
  int head = xcd * 2 + (jj >> 7);
  int sub = jj & 127;
  int bb = head >> 3, hh = head & 7;
  int q0 = sub << 4;

  int t = threadIdx.x;
  int lane = t & 63, wv = t >> 6;
  int cg = lane >> 4, ln = lane & 15;
  int swzl = SWZ(ln);
  int k_base = wv * 256;

  const __bf16* Qr = Qh + ((long)head * 2048 + q0 + ln) * 64;
  bf16x8 qf0 = *reinterpret_cast<const bf16x8*>(Qr + cg * 8);
  bf16x8 qf1 = *reinterpret_cast<const bf16x8*>(Qr + 32 + cg * 8);
  float2 st = stats[(head << 11) + q0 + ln];
  float mu = st.x, rs = st.y;

  const __bf16* Kb = Kh + (long)head * 2048 * 64;

  // ---- QK + sin -> stash (swizzled bf16), Z in-lane ----
  float Z = 0.f;
  char* myrow = reinterpret_cast<char*>(stash) + ln * 4096;
  int kb2 = k_base * 2;
#pragma unroll
  for (int w = 0; w < 8; w++) {
    int kb = k_base + w * 32;
    const __bf16* Kr0 = Kb + (long)(kb + ln) * 64;
    const __bf16* Kr1 = Kb + (long)(kb + 16 + ln) * 64;
    f32x4 d0 = (f32x4){0.f, 0.f, 0.f, 0.f}, d1 = (f32x4){0.f, 0.f, 0.f, 0.f};
    d0 = __builtin_amdgcn_mfma_f32_16x16x32_bf16(
        *reinterpret_cast<const bf16x8*>(Kr0 + cg * 8), qf0, d0, 0, 0, 0);
    d0 = __builtin_amdgcn_mfma_f32_16x16x32_bf16(
        *reinterpret_cast<const bf16x8*>(Kr0 + 32 + cg * 8), qf1, d0, 0, 0, 0);
    d1 = __builtin_amdgcn_mfma_f32_16x16x32_bf16(
        *reinterpret_cast<const bf16x8*>(Kr1 + cg * 8), qf0, d1, 0, 0, 0);
    d1 = __builtin_amdgcn_mfma_f32_16x16x32_bf16(
        *reinterpret_cast<const bf16x8*>(Kr1 + 32 + cg * 8), qf1, d1, 0, 0, 0);
    bf16x4 w0, w1;
#pragma unroll
    for (int r4 = 0; r4 < 4; r4++) {
      float p0 = 1.f + __sinf(1.25f * (d0[r4] - mu) * rs);
      float p1 = 1.f + __sinf(1.25f * (d1[r4] - mu) * rs);
      Z += p0 + p1;
      w0[r4] = (__bf16)p0;
      w1[r4] = (__bf16)p1;
    }
    int boff = kb2 + w * 64 + cg * 8;
    *reinterpret_cast<bf16x4*>(myrow + (boff ^ swzl)) = w0;
    *reinterpret_cast<bf16x4*>(myrow + ((boff + 32) ^ swzl)) = w1;
  }
  Z += __shfl_xor(Z, 16); Z += __shfl_xor(Z, 32);
  if (lane < 16) red2[wv][ln] = Z;
  __syncthreads();  // barrier A: stash + red2 ready

  // ---- scores write: normalized fp32, coalesced ----
  {
    int r = t >> 5, c0 = t & 31;
    float z8 = 0.f;
#pragma unroll
    for (int w = 0; w < 8; w++) z8 += red2[w][r];
    float invZ = 1.f / z8;
    const char* rrow = reinterpret_cast<const char*>(stash) + r * 4096;
    int swzr = SWZ(r);
    float* srow = sco + ((long)head * 2048 + q0 + r) * 2048;
#pragma unroll
    for (int j = 0; j < 8; j++) {
      int chunk = c0 + j * 32;
      bf16x8 v = *reinterpret_cast<const bf16x8*>(rrow + ((chunk * 16) ^ swzr));
      float4 o0, o1;
      o0.x = (float)v[0] * invZ; o0.y = (float)v[1] * invZ;
      o0.z = (float)v[2] * invZ; o0.w = (float)v[3] * invZ;
      o1.x = (float)v[4] * invZ; o1.y = (float)v[5] * invZ;
      o1.z = (float)v[6] * invZ; o1.w = (float)v[7] * invZ;
      *reinterpret_cast<float4*>(srow + chunk * 8) = o0;
      *reinterpret_cast<float4*>(srow + chunk * 8 + 4) = o1;
    }
  }

  // ---- PV (swapped): hvT[d][q] += Vp-frag x P-frag, dense panel loads ----
  f32x4 hacc[4];
#pragma unroll
  for (int dt = 0; dt < 4; dt++) hacc[dt] = (f32x4){0.f, 0.f, 0.f, 0.f};
  {
    float z8 = 0.f;
#pragma unroll
    for (int w = 0; w < 8; w++) z8 += red2[w][ln];
    float invZ = 1.f / z8;
    const __bf16* vhead = Vp + (long)head * 131072;
    const char* prow = reinterpret_cast<const char*>(stash) + ln * 4096;
#pragma unroll
    for (int w = 0; w < 8; w++) {
      int kb = k_base + w * 32;
      const __bf16* panel = vhead + (kb >> 5) * 2048;
      bf16x8 pfrag = *reinterpret_cast<const bf16x8*>(
          prow + ((kb2 + w * 64 + cg * 16) ^ swzl));
#pragma unroll
      for (int dt = 0; dt < 4; dt++) {
        bf16x8 vf = *reinterpret_cast<const bf16x8*>(panel + (dt * 16 + ln) * 32 + cg * 8);
        hacc[dt] = __builtin_amdgcn_mfma_f32_16x16x32_bf16(vf, pfrag, hacc[dt], 0, 0, 0);
      }
    }
#pragma unroll
    for (int dt = 0; dt < 4; dt++)
#pragma unroll
      for (int r4 = 0; r4 < 4; r4++) hacc[dt][r4] *= invZ;
  }
  __syncthreads();  // barrier B: all stash reads done

  // write hvT partials into stash region (fp32, [wv][q=ln][d] swizzled 16B)
  {
    char* hbase = reinterpret_cast<char*>(stash) + wv * 4096 + ln * 256;
#pragma unroll
    for (int dt = 0; dt < 4; dt++) {
      int doff = (dt * 16 + cg * 4) * 4;
      *reinterpret_cast<f32x4*>(hbase + (doff ^ swzl)) = hacc[dt];
    }
  }
  __syncthreads();  // barrier C

  // reduce 8 partials, write hv bf16: thread t -> (q = t>>5, d0 = (t&31)*2)
  {
    int q = t >> 5, d0 = (t & 31) * 2;
    int swzq = SWZ(q);
    int slot = ((d0 & ~3) * 4) ^ swzq;
    int rem = (d0 & 3) * 4;
    float a0 = 0.f, a1 = 0.f;
#pragma unroll
    for (int w = 0; w < 8; w++) {
      const char* p = reinterpret_cast<const char*>(stash) + w * 4096 + q * 256 + slot + rem;
      float2 vv = *reinterpret_cast<const float2*>(p);
      a0 += vv.x; a1 += vv.y;
    }
    bf16x2 hw;
    hw[0] = (__bf16)a0; hw[1] = (__bf16)a1;
    *reinterpret_cast<bf16x2*>(hv + (long)(bb * 2048 + q0 + q) * 512 + hh * 64 + d0) = hw;
  }
}

// ---------------- launch ----------------
extern "C" void kernel_launch(void* const* d_in, const int* in_sizes, int n_in,
                              void* d_out, int out_size, void* d_ws, size_t ws_size,
                              hipStream_t stream) {
  const float* x = (const float*)d_in[0];
  const float* norm_w = (const float*)d_in[1];
  const float* norm_b = (const float*)d_in[2];
  const float* qvk_w = (const float*)d_in[3];
  const float* qvk_b = (const float*)d_in[4];
  const float* concat_w = (const float*)d_in[5];
  const float* concat_b = (const float*)d_in[6];
  const float* mlp_norm_w = (const float*)d_in[7];
  const float* mlp_norm_b = (const float*)d_in[8];
  const float* mlp1_w = (const float*)d_in[9];
  const float* mlp1_b = (const float*)d_in[10];
  const float* mlp2_w = (const float*)d_in[11];
  const float* mlp2_b = (const float*)d_in[12];

  char* ws = (char*)d_ws;
  __bf16* qvk_wT = (__bf16*)(ws + 0);          // 1536x512
  __bf16* concat_wT = (__bf16*)(ws + 1572864); // 512x512
  __bf16* mlp1_wT = (__bf16*)(ws + 2097152);   // 1024x512
  __bf16* mlp2_wT = (__bf16*)(ws + 3145728);   // 512x1024
  __bf16* xn = (__bf16*)(ws + 4194304);        // 4096x512
  __bf16* Qh = (__bf16*)(ws + 8388608);        // (16 heads)x2048x64
  __bf16* Kh = (__bf16*)(ws + 12582912);       // (16 heads)x2048x64
  __bf16* Vp = (__bf16*)(ws + 16777216);       // (16 heads) 32-k panels
  __bf16* hv = (__bf16*)(ws + 20971520);       // 4096x512
  float* gpart = (float*)(ws + 25165824);      // 8MB (overwritten by attout later)
  float* attout = (float*)(ws + 25165824);     // 4096x512 fp32 (after attn2)
  float* kpart = (float*)(ws + 33554432);      // 128KB  (in a_b region)
  float* G = (float*)(ws + 33685504);          // 256KB
  float* kbar = (float*)(ws + 33947648);       // 4KB
  float2* stats = (float2*)(ws + 33951744);    // 256KB
  __bf16* a_b = (__bf16*)(ws + 33554432);      // 4096x512 (after attn2)
  __bf16* h_b = (__bf16*)(ws + 37748736);      // 4096x1024

  float* out0 = (float*)d_out;
  float* sco = out0 + 2097152;  // scores (B,H,S,S) fp32

  wtrans_kernel<<<3072, 256, 0, stream>>>(qvk_w, qvk_wT, 512, 1536);
  wtrans_kernel<<<1024, 256, 0, stream>>>(concat_w, concat_wT, 512, 512);
  wtrans_kernel<<<2048, 256, 0, stream>>>(mlp1_w, mlp1_wT, 512, 1024);
  wtrans_kernel<<<2048, 256, 0, stream>>>(mlp2_w, mlp2_wT, 1024, 512);

  ln_kernel<<<4096, 256, 0, stream>>>(x, norm_w, norm_b, xn);

  // qkv = relu(xn @ qvk_w + b); Q,K head-contig; V panels
  gemm_kernel<1, 2, false><<<dim3(12, 32), 256, 0, stream>>>(
      xn, qvk_wT, qvk_b, nullptr, nullptr, Qh, Kh, Vp, 512, 512, 1536, 512);

  // per-head Gram + kbar -> per-row stats
  gram_kernel<<<512, 256, 0, stream>>>(Kh, gpart, kpart);
  greduce_kernel<<<260, 256, 0, stream>>>(gpart, kpart, G, kbar);
  stats_kernel<<<512, 256, 0, stream>>>(Qh, G, kbar, stats);

  // fused attention (scores -> out1, hv bf16)
  attn2_kernel<<<2048, 512, 0, stream>>>(Qh, Kh, Vp, stats, sco, hv);

  // attout = hv @ concat_w + b + x (fp32)
  gemm_kernel<0, 0, true><<<dim3(4, 32), 256, 0, stream>>>(
      hv, concat_wT, concat_b, x, attout, nullptr, nullptr, nullptr, 512, 512, 512, 512);

  ln_kernel<<<4096, 256, 0, stream>>>(attout, mlp_norm_w, mlp_norm_b, a_b);

  // h = gelu(a @ mlp1_w + b)
  gemm_kernel<2, 1, false><<<dim3(8, 32), 256, 0, stream>>>(
      a_b, mlp1_wT, mlp1_b, nullptr, nullptr, h_b, nullptr, nullptr, 512, 512, 1024, 512);

  // out0 = h @ mlp2_w + b + attout
  gemm_kernel<0, 0, true><<<dim3(4, 32), 256, 0, stream>>>(
      h_b, mlp2_wT, mlp2_b, attout, out0, nullptr, nullptr, nullptr, 1024, 1024, 512, 1024);
}